// Round 12
// baseline (167.367 us; speedup 1.0000x reference)
//
#include <hip/hip_runtime.h>

#define BB 16
#define TT 8192
#define NN 128                     // N_PRE == N_POST
constexpr int CHUNK = 256;         // time-steps per chunk
constexpr int NCH   = BB * TT / CHUNK;   // 512 chunks
constexpr int NBLK  = NCH / 2;           // 256 blocks, 2 chunks each
constexpr int OUTN  = NN * NN;           // 16384
constexpr int GS    = 264;         // bufG row stride in halves (528 B, 16B-aligned)
constexpr int SLOTS = OUTN / 2;    // 8192 packed u32 slots per block-slice
constexpr int PROWS = 315;         // staged post rows per chunk: (t0, t0+315]

typedef _Float16 f16x8 __attribute__((ext_vector_type(8)));
typedef _Float16 f16x2 __attribute__((ext_vector_type(2)));
typedef float    f32x4 __attribute__((ext_vector_type(4)));

__device__ __forceinline__ unsigned short h16(float x) {
    _Float16 h = (_Float16)x;
    return __builtin_bit_cast(unsigned short, h);
}
__device__ __forceinline__ unsigned int pack2(float x, float y) {
    return (unsigned int)h16(x) | ((unsigned int)h16(y) << 16);
}
__device__ __forceinline__ float2 ldL(const unsigned short* p_lds, int m, int q0) {
    const unsigned int v = *(const unsigned int*)&p_lds[m * NN + q0];
    const f16x2 h = __builtin_bit_cast(f16x2, v);
    return make_float2((float)h[0], (float)h[1]);
}

// grid 256 x 512 threads, 1 block/CU. Block = chunks 2*bi, 2*bi+1 (same batch).
// r12: identical algorithm to r11 but code-compacted (single chunk loop, partially
// unrolled filter init) to test the I$-streaming theory of the 53 us plateau.
template<bool ATOMIC>
__global__ __launch_bounds__(512, 4)
void stdp_main(const float* __restrict__ pre, const float* __restrict__ post,
               const int* __restrict__ dtp,
               unsigned int* __restrict__ part, float* __restrict__ wpost,
               float* __restrict__ outat)
{
    __shared__ __align__(16) unsigned short bufP[PROWS * NN];   // 80,640 B post tile
    __shared__ __align__(16) unsigned short bufG[NN * GS];      // 67,584 B g tile
    __shared__ float lds_ps[8 * NN];                            // 4 KB

    const int tid    = threadIdx.x;
    const int bi     = blockIdx.x;
    const int c0g    = bi * 2;           // global chunk ids c0g, c0g+1 (same batch)
    const int b      = c0g >> 5;
    const int chunk0 = c0g & 31;         // even, 0..30
    const int t00    = chunk0 * CHUNK;
    const int wv     = tid >> 6;         // wave 0..7
    const int lane   = tid & 63;

    const float dtf = (float)(*dtp);
    const float r   = expf(-dtf * (1.0f / 20.0f));

    const float* pb = post + (size_t)b * TT * NN;
    const float* ab = pre  + (size_t)b * TT * NN;

    const int sc = tid & 31;             // staging: float4 column
    const int mr = tid >> 5;             // staging: starting row (0..15)
    const int q0 = lane * 2;

    // ---------- stage c0 post tile (chunk0 even => t00+315 < TT, no guard) ----------
    for (int m = mr; m < PROWS; m += 16) {
        const int t = t00 + 1 + m;
        const float4 v = *(const float4*)(pb + (size_t)t * NN + sc * 4);
        *(uint2*)&bufP[m * NN + sc * 4] = make_uint2(pack2(v.x, v.y), pack2(v.z, v.w));
    }
    __syncthreads();

    f32x4 acc[8];
    #pragma unroll
    for (int qt = 0; qt < 8; ++qt) acc[qt] = (f32x4){0.f, 0.f, 0.f, 0.f};

    const int pr0 = wv * 16;

    #pragma unroll 1
    for (int cc = 0; cc < 2; ++cc) {
        const int t0 = t00 + cc * CHUNK;

        // ---------- filter window wv (32 steps), 2 q per lane ----------
        const int base = wv * 32;
        float ps0 = 0.f, ps1 = 0.f;
        unsigned int pk0[16], pk1[16];
        {
            float2 p  = ldL(bufP, base + 31, q0);   // tau=1: P[ts+32]
            float wt  = r;
            float gx = r * p.x, gy = r * p.y;
            ps0 += p.x; ps1 += p.y;
            #pragma unroll 2
            for (int tau = 2; tau <= 59; ++tau) {
                wt *= r;
                p = ldL(bufP, base + 30 + tau, q0);
                gx = fmaf(wt, p.x, gx);
                gy = fmaf(wt, p.y, gy);
            }
            const float r60 = wt * r;               // r^60, consistent weights
            pk0[15] = (unsigned int)h16(gx) << 16;
            pk1[15] = (unsigned int)h16(gy) << 16;
            // recurrence: g[t] = r*(g[t+1]+P(t+1)) - r^60*P(t+60)  (unrolled: pk indexing)
            #pragma unroll
            for (int c = 30; c >= 0; --c) {
                const float2 p1  = ldL(bufP, base + c,      q0);
                const float2 p60 = ldL(bufP, base + c + 59, q0);
                gx = r * (gx + p1.x) - r60 * p60.x;
                gy = r * (gy + p1.y) - r60 * p60.y;
                ps0 += p1.x; ps1 += p1.y;
                if (c & 1) {
                    pk0[c >> 1] = (unsigned int)h16(gx) << 16;
                    pk1[c >> 1] = (unsigned int)h16(gy) << 16;
                } else {
                    pk0[c >> 1] |= h16(gx);
                    pk1[c >> 1] |= h16(gy);
                }
            }
        }
        __syncthreads();    // (a) all bufP reads done; prev MFMA's bufG reads done

        // ---------- dump g + ps ----------
        {
            unsigned short* d0 = &bufG[q0 * GS + base];
            unsigned short* d1 = &bufG[(q0 + 1) * GS + base];
            #pragma unroll
            for (int s = 0; s < 4; ++s) {
                *(uint4*)(d0 + 8*s) = make_uint4(pk0[4*s], pk0[4*s+1], pk0[4*s+2], pk0[4*s+3]);
                *(uint4*)(d1 + 8*s) = make_uint4(pk1[4*s], pk1[4*s+1], pk1[4*s+2], pk1[4*s+3]);
            }
            lds_ps[wv * NN + q0]     = ps0;
            lds_ps[wv * NN + q0 + 1] = ps1;
        }

        // ---------- stage c1 into bufP (cc==0 only; filter-c0 reads done at (a)) ----------
        if (cc == 0) {
            for (int m = mr; m < PROWS; m += 16) {
                const int t = t00 + CHUNK + 1 + m;
                float4 v = make_float4(0.f, 0.f, 0.f, 0.f);
                if (t < TT) v = *(const float4*)(pb + (size_t)t * NN + sc * 4);
                *(uint2*)&bufP[m * NN + sc * 4] = make_uint2(pack2(v.x, v.y), pack2(v.z, v.w));
            }
        }
        __syncthreads();    // (b) g + ps visible; bufP(c1) visible for next filter

        // ---------- wpost(cc) ----------
        if (tid < NN) {
            float s = 0.f;
            #pragma unroll
            for (int w = 0; w < 8; ++w) s += lds_ps[w * NN + tid];
            if (chunk0 == 0 && cc == 0) s += pb[tid];   // missing t=0 row, once per batch
            if constexpr (ATOMIC) atomicAdd(&wpost[tid], s);
            else wpost[(size_t)tid * NCH + c0g + cc] = s;
        }

        // ---------- MFMA: acc += pre(t0..t0+256)^T @ g, K=256 ----------
        {
            const float* abase = ab + (size_t)(t0 + (lane >> 4) * 8) * NN + pr0 + (lane & 15);
            float an[8];
            #pragma unroll
            for (int j = 0; j < 8; ++j) an[j] = abase[(size_t)j * NN];
            #pragma unroll
            for (int ks = 0; ks < 8; ++ks) {
                f16x8 af;
                #pragma unroll
                for (int j = 0; j < 8; ++j) af[j] = (_Float16)an[j];    // 0/1 exact
                if (ks < 7) {
                    const float* src = abase + (size_t)((ks + 1) * 32) * NN;
                    #pragma unroll
                    for (int j = 0; j < 8; ++j) an[j] = src[(size_t)j * NN];
                }
                const int koff = ks * 32 + (lane >> 4) * 8;
                #pragma unroll
                for (int qt = 0; qt < 8; ++qt) {
                    const f16x8 bf = *(const f16x8*)&bufG[(qt * 16 + (lane & 15)) * GS + koff];
                    acc[qt] = __builtin_amdgcn_mfma_f32_16x16x32_f16(af, bf, acc[qt], 0, 0, 0);
                }
            }
        }
    }

    // ---------- write combined partial: u32-packed f16 pairs, coalesced ----------
    if constexpr (!ATOMIC) {
        unsigned int* dst = part + ((size_t)bi * 8 + wv) * 1024 + lane;
        #pragma unroll
        for (int qt = 0; qt < 8; ++qt)
            #pragma unroll
            for (int rp = 0; rp < 2; ++rp)
                dst[qt * 128 + rp * 64] = pack2(acc[qt][2 * rp], acc[qt][2 * rp + 1]);
    } else {
        #pragma unroll
        for (int qt = 0; qt < 8; ++qt)
            #pragma unroll
            for (int rg = 0; rg < 4; ++rg) {
                const int prow = pr0 + (lane >> 4) * 4 + rg;
                const int qcol = qt * 16 + (lane & 15);
                atomicAdd(&outat[prow * NN + qcol], acc[qt][rg]);
            }
    }
}

// fused split-K reduce + hfac + epilogue: 128 blocks x 512 thr.
// Each block's 64 slots share one qt => 16 distinct q: hfac computed in-kernel.
__global__ __launch_bounds__(512)
void finalize_ws(const unsigned int* __restrict__ part, const float* __restrict__ wpost,
                 const int* __restrict__ dtp, const float* __restrict__ W,
                 float* __restrict__ out)
{
    __shared__ float2 red[512];
    __shared__ float  hfs[16];
    const int s    = threadIdx.x & 63;        // slot within block's 64
    const int kq   = threadIdx.x >> 6;        // 0..7
    const int slot = blockIdx.x * 64 + s;     // 0..8191
    const int qt   = (slot >> 7) & 7;         // fixed for whole block
    const int qbase = qt * 16;

    // hfac: 32 threads per q, shfl reduce over wpost[q][0..NCH)
    {
        const int qi = threadIdx.x >> 5;      // 0..15
        const int pr = threadIdx.x & 31;
        float hsum = 0.f;
        const float* wq = wpost + (size_t)(qbase + qi) * NCH;
        #pragma unroll 4
        for (int k = pr; k < NCH; k += 32) hsum += wq[k];
        #pragma unroll
        for (int off = 16; off; off >>= 1) hsum += __shfl_down(hsum, off, 32);
        if (pr == 0) {
            const float dtf   = (float)(*dtp);
            const float alpha = dtf * 1e-3f;
            hfs[qi] = -0.001f * (alpha * (hsum * (1.0f / (float)(BB * TT)) - 0.1f));
        }
    }

    float sx = 0.f, sy = 0.f;
    #pragma unroll 8
    for (int k = kq * (NBLK / 8); k < (kq + 1) * (NBLK / 8); ++k) {
        const unsigned int v = part[(size_t)k * SLOTS + slot];
        const f16x2 h = __builtin_bit_cast(f16x2, v);
        sx += (float)h[0];
        sy += (float)h[1];
    }
    red[threadIdx.x] = make_float2(sx, sy);
    __syncthreads();
    if (threadIdx.x < 64) {
        float tx = red[s].x, ty = red[s].y;
        #pragma unroll
        for (int g = 1; g < 8; ++g) {
            const float2 v = red[g * 64 + s];
            tx += v.x; ty += v.y;
        }
        // un-permute slot -> (p, q)
        const int lane = slot & 63;
        const int rp   = (slot >> 6) & 1;
        const int wv   = slot >> 10;
        const int p    = wv * 16 + ((lane >> 4) << 2) + rp * 2;
        const int qi   = lane & 15;
        const int q    = qbase + qi;
        const float scale = (float)((0.005 - 0.00525) / (double)(BB * TT));
        const float hf = hfs[qi];
        out[p * NN + q]       = fmaf(tx, scale, hf * W[p * NN + q]);
        out[(p + 1) * NN + q] = fmaf(ty, scale, hf * W[(p + 1) * NN + q]);
    }
}

// fallback epilogue when S was atomically accumulated in d_out
__global__ void finalize_at(const float* __restrict__ wpost, const int* __restrict__ dtp,
                            const float* __restrict__ W, float* __restrict__ out)
{
    const int i = (blockIdx.x * 256 + threadIdx.x) * 2;
    const int q = i & 127;
    const float scale = (float)((0.005 - 0.00525) / (double)(BB * TT));
    const float dtf   = (float)(*dtp);
    const float alpha = dtf * 1e-3f;
    const float inv   = 1.0f / (float)(BB * TT);
    const float hf0   = -0.001f * (alpha * (wpost[q]     * inv - 0.1f));
    const float hf1   = -0.001f * (alpha * (wpost[q + 1] * inv - 0.1f));
    float2 sv = *(const float2*)(out + i);
    float2 w  = *(const float2*)(W + i);
    float2 o;
    o.x = fmaf(sv.x, scale, hf0 * w.x);
    o.y = fmaf(sv.y, scale, hf1 * w.y);
    *(float2*)(out + i) = o;
}

extern "C" void kernel_launch(void* const* d_in, const int* in_sizes, int n_in,
                              void* d_out, int out_size, void* d_ws, size_t ws_size,
                              hipStream_t stream)
{
    const float* pre  = (const float*)d_in[0];
    const float* post = (const float*)d_in[1];
    const float* W    = (const float*)d_in[2];
    const int*   dtp  = (const int*)d_in[3];
    float* out = (float*)d_out;

    const size_t part_bytes  = (size_t)NBLK * SLOTS * sizeof(unsigned int); // 8 MiB
    const size_t wpost_bytes = (size_t)NN * NCH * sizeof(float);            // 256 KiB
    const size_t need = part_bytes + wpost_bytes;

    if (ws_size >= need) {
        unsigned int* part = (unsigned int*)d_ws;
        float* wpost       = (float*)((char*)d_ws + part_bytes);
        hipLaunchKernelGGL((stdp_main<false>), dim3(NBLK), dim3(512), 0, stream,
                           pre, post, dtp, part, wpost, (float*)nullptr);
        hipLaunchKernelGGL(finalize_ws, dim3(SLOTS / 64), dim3(512), 0, stream,
                           part, wpost, dtp, W, out);
    } else {
        // atomic fallback: needs only 512 B of workspace
        float* wpost = (float*)d_ws;
        hipMemsetAsync(d_out, 0, OUTN * sizeof(float), stream);
        hipMemsetAsync(wpost, 0, NN * sizeof(float), stream);
        hipLaunchKernelGGL((stdp_main<true>), dim3(NBLK), dim3(512), 0, stream,
                           pre, post, dtp, (unsigned int*)nullptr, wpost, out);
        hipLaunchKernelGGL(finalize_at, dim3(OUTN / 512), dim3(256), 0, stream,
                           wpost, dtp, W, out);
    }
}

// Round 13
// 159.196 us; speedup vs baseline: 1.0513x; 1.0513x over previous
//
#include <hip/hip_runtime.h>

#define BB 16
#define TT 8192
#define NN 128                     // N_PRE == N_POST
constexpr int CHUNK = 256;         // time-steps per chunk
constexpr int NCH   = BB * TT / CHUNK;   // 512 chunks
constexpr int NBLK  = NCH / 2;           // 256 blocks, 2 chunks each
constexpr int OUTN  = NN * NN;           // 16384
constexpr int GS    = 264;         // bufG row stride in halves (528 B, 16B-aligned)
constexpr int SLOTS = OUTN / 2;    // 8192 packed u32 slots per block-slice
constexpr int PROWS = 315;         // staged post rows per chunk: (t0, t0+315]

typedef _Float16 f16x8 __attribute__((ext_vector_type(8)));
typedef _Float16 f16x2 __attribute__((ext_vector_type(2)));
typedef float    f32x4 __attribute__((ext_vector_type(4)));

__device__ __forceinline__ unsigned short h16(float x) {
    _Float16 h = (_Float16)x;
    return __builtin_bit_cast(unsigned short, h);
}
__device__ __forceinline__ unsigned int pack2(float x, float y) {
    return (unsigned int)h16(x) | ((unsigned int)h16(y) << 16);
}
__device__ __forceinline__ float2 ldL(const unsigned short* p_lds, int m, int q0) {
    const unsigned int v = *(const unsigned int*)&p_lds[m * NN + q0];
    const f16x2 h = __builtin_bit_cast(f16x2, v);
    return make_float2((float)h[0], (float)h[1]);
}

// grid 256 x 512 threads, 1 block/CU (152 KB LDS). Block = chunks 2*bi, 2*bi+1.
// r13 == r11 verbatim (measured best: stdp 52.7 us, total 158.3 us).
// Pipeline: stage c0 -> issue c1 loads -> filter c0 (overlaps c1 drain) ->
// g0 dump -> barrier -> c1 regs->bufP -> MFMA c0 -> barrier -> filter c1 ->
// g1 dump -> barrier -> MFMA c1 (acc over both) -> single combined partial.
template<bool ATOMIC>
__global__ __launch_bounds__(512, 2)
void stdp_main(const float* __restrict__ pre, const float* __restrict__ post,
               const int* __restrict__ dtp,
               unsigned int* __restrict__ part, float* __restrict__ wpost,
               float* __restrict__ outat)
{
    __shared__ __align__(16) unsigned short bufP[PROWS * NN];   // 80,640 B post tile
    __shared__ __align__(16) unsigned short bufG[NN * GS];      // 67,584 B g tile
    __shared__ float lds_ps[8 * NN];                            // 4 KB

    const int tid    = threadIdx.x;
    const int bi     = blockIdx.x;
    const int c0g    = bi * 2;           // global chunk ids c0g, c0g+1 (same batch)
    const int b      = c0g >> 5;
    const int chunk0 = c0g & 31;         // even, 0..30
    const int t00    = chunk0 * CHUNK;
    const int t01    = t00 + CHUNK;
    const int wv     = tid >> 6;         // wave 0..7
    const int lane   = tid & 63;

    const float dtf = (float)(*dtp);
    const float r   = expf(-dtf * (1.0f / 20.0f));

    const float* pb = post + (size_t)b * TT * NN;
    const float* ab = pre  + (size_t)b * TT * NN;

    const int sc = tid & 31;             // staging: float4 column
    const int mr = tid >> 5;             // staging: starting row (0..15)

    // ---------- stage c0 post tile into bufP ----------
    for (int m = mr; m < PROWS; m += 16) {
        const int t = t00 + 1 + m;       // c0 even => t00+315 <= 7995 < TT, no guard needed
        const float4 v = *(const float4*)(pb + (size_t)t * NN + sc * 4);
        *(uint2*)&bufP[m * NN + sc * 4] = make_uint2(pack2(v.x, v.y), pack2(v.z, v.w));
    }
    __syncthreads();

    // ---------- issue c1 staging loads into registers (drain overlaps filter c0) ----------
    float4 va[20];
    #pragma unroll
    for (int i = 0; i < 20; ++i) {
        const int m = mr + i * 16;
        const int t = t01 + 1 + m;
        va[i] = make_float4(0.f, 0.f, 0.f, 0.f);
        if (m < PROWS && t < TT) va[i] = *(const float4*)(pb + (size_t)t * NN + sc * 4);
    }

    const int q0 = lane * 2;

    // ---------- filter c0: window wv (32 steps), 2 q per lane ----------
    unsigned int pk0[16], pk1[16];
    float ps0, ps1;
    #define FILTER_PHASE(SRC) {                                               \
        const int base = wv * 32;                                             \
        ps0 = 0.f; ps1 = 0.f;                                                 \
        float2 p  = ldL(SRC, base + 31, q0);                                  \
        float wt  = r;                                                        \
        float gx = r * p.x, gy = r * p.y;                                     \
        ps0 += p.x; ps1 += p.y;                                               \
        _Pragma("unroll")                                                     \
        for (int tau = 2; tau <= 59; ++tau) {                                 \
            wt *= r;                                                          \
            p = ldL(SRC, base + 30 + tau, q0);                                \
            gx = fmaf(wt, p.x, gx);                                           \
            gy = fmaf(wt, p.y, gy);                                           \
        }                                                                     \
        const float r60 = wt * r;                                             \
        pk0[15] = (unsigned int)h16(gx) << 16;                                \
        pk1[15] = (unsigned int)h16(gy) << 16;                                \
        _Pragma("unroll")                                                     \
        for (int c = 30; c >= 0; --c) {                                       \
            const float2 p1  = ldL(SRC, base + c,      q0);                   \
            const float2 p60 = ldL(SRC, base + c + 59, q0);                   \
            gx = r * (gx + p1.x) - r60 * p60.x;                               \
            gy = r * (gy + p1.y) - r60 * p60.y;                               \
            ps0 += p1.x; ps1 += p1.y;                                         \
            if (c & 1) {                                                      \
                pk0[c >> 1] = (unsigned int)h16(gx) << 16;                    \
                pk1[c >> 1] = (unsigned int)h16(gy) << 16;                    \
            } else {                                                          \
                pk0[c >> 1] |= h16(gx);                                       \
                pk1[c >> 1] |= h16(gy);                                       \
            }                                                                 \
        }                                                                     \
    }
    #define DUMP_G() {                                                        \
        unsigned short* d0 = &bufG[q0 * GS + wv * 32];                        \
        unsigned short* d1 = &bufG[(q0 + 1) * GS + wv * 32];                  \
        _Pragma("unroll")                                                     \
        for (int s = 0; s < 4; ++s) {                                         \
            *(uint4*)(d0 + 8*s) = make_uint4(pk0[4*s], pk0[4*s+1], pk0[4*s+2], pk0[4*s+3]); \
            *(uint4*)(d1 + 8*s) = make_uint4(pk1[4*s], pk1[4*s+1], pk1[4*s+2], pk1[4*s+3]); \
        }                                                                     \
        lds_ps[wv * NN + q0]     = ps0;                                       \
        lds_ps[wv * NN + q0 + 1] = ps1;                                       \
    }

    FILTER_PHASE(bufP)
    DUMP_G()
    __syncthreads();                     // bufP reads done; g0 + ps visible; c1 loads drained

    // ---------- store c1 post tile into bufP (safe: filter c0 complete) ----------
    #pragma unroll
    for (int i = 0; i < 20; ++i) {
        const int m = mr + i * 16;
        if (m < PROWS)
            *(uint2*)&bufP[m * NN + sc * 4] =
                make_uint2(pack2(va[i].x, va[i].y), pack2(va[i].z, va[i].w));
    }

    // ---------- wpost c0 ----------
    if (tid < NN) {
        float s = 0.f;
        #pragma unroll
        for (int w = 0; w < 8; ++w) s += lds_ps[w * NN + tid];
        if (chunk0 == 0) s += pb[tid];   // window (t0,t0+256] misses t=0 row once per batch
        if constexpr (ATOMIC) atomicAdd(&wpost[tid], s);
        else wpost[(size_t)tid * NCH + c0g] = s;
    }

    // ---------- MFMA c0 ----------
    const int pr0 = wv * 16;
    f32x4 acc[8];
    #pragma unroll
    for (int qt = 0; qt < 8; ++qt) acc[qt] = (f32x4){0.f, 0.f, 0.f, 0.f};

    #define MFMA_PHASE(T0) {                                                  \
        const float* abase = ab + (size_t)((T0) + (lane >> 4) * 8) * NN + pr0 + (lane & 15); \
        float an[8];                                                          \
        _Pragma("unroll")                                                     \
        for (int j = 0; j < 8; ++j) an[j] = abase[(size_t)j * NN];            \
        _Pragma("unroll")                                                     \
        for (int ks = 0; ks < 8; ++ks) {                                      \
            f16x8 af;                                                         \
            _Pragma("unroll")                                                 \
            for (int j = 0; j < 8; ++j) af[j] = (_Float16)an[j];              \
            if (ks < 7) {                                                     \
                const float* src = abase + (size_t)((ks + 1) * 32) * NN;      \
                _Pragma("unroll")                                             \
                for (int j = 0; j < 8; ++j) an[j] = src[(size_t)j * NN];      \
            }                                                                 \
            const int koff = ks * 32 + (lane >> 4) * 8;                       \
            _Pragma("unroll")                                                 \
            for (int qt = 0; qt < 8; ++qt) {                                  \
                const f16x8 bf = *(const f16x8*)&bufG[(qt * 16 + (lane & 15)) * GS + koff]; \
                acc[qt] = __builtin_amdgcn_mfma_f32_16x16x32_f16(af, bf, acc[qt], 0, 0, 0); \
            }                                                                 \
        }                                                                     \
    }

    MFMA_PHASE(t00)
    __syncthreads();                     // bufG reads done; bufP(c1) stores visible

    // ---------- filter c1 + dump g1 ----------
    FILTER_PHASE(bufP)
    DUMP_G()
    __syncthreads();

    // ---------- wpost c1 ----------
    if (tid < NN) {
        float s = 0.f;
        #pragma unroll
        for (int w = 0; w < 8; ++w) s += lds_ps[w * NN + tid];
        if constexpr (ATOMIC) atomicAdd(&wpost[tid], s);
        else wpost[(size_t)tid * NCH + c0g + 1] = s;
    }

    // ---------- MFMA c1 (accumulates onto acc) ----------
    MFMA_PHASE(t01)

    // ---------- write combined partial: u32-packed f16 pairs, coalesced ----------
    if constexpr (!ATOMIC) {
        unsigned int* dst = part + ((size_t)bi * 8 + wv) * 1024 + lane;
        #pragma unroll
        for (int qt = 0; qt < 8; ++qt)
            #pragma unroll
            for (int rp = 0; rp < 2; ++rp)
                dst[qt * 128 + rp * 64] = pack2(acc[qt][2 * rp], acc[qt][2 * rp + 1]);
    } else {
        #pragma unroll
        for (int qt = 0; qt < 8; ++qt)
            #pragma unroll
            for (int rg = 0; rg < 4; ++rg) {
                const int prow = pr0 + (lane >> 4) * 4 + rg;
                const int qcol = qt * 16 + (lane & 15);
                atomicAdd(&outat[prow * NN + qcol], acc[qt][rg]);
            }
    }
    #undef FILTER_PHASE
    #undef DUMP_G
    #undef MFMA_PHASE
}

// fused split-K reduce + hfac + epilogue: 128 blocks x 512 thr.
// Each block's 64 slots share one qt => 16 distinct q: hfac computed in-kernel.
__global__ __launch_bounds__(512)
void finalize_ws(const unsigned int* __restrict__ part, const float* __restrict__ wpost,
                 const int* __restrict__ dtp, const float* __restrict__ W,
                 float* __restrict__ out)
{
    __shared__ float2 red[512];
    __shared__ float  hfs[16];
    const int s    = threadIdx.x & 63;        // slot within block's 64
    const int kq   = threadIdx.x >> 6;        // 0..7
    const int slot = blockIdx.x * 64 + s;     // 0..8191
    const int qt   = (slot >> 7) & 7;         // fixed for whole block
    const int qbase = qt * 16;

    // hfac: 32 threads per q, shfl reduce over wpost[q][0..NCH)
    {
        const int qi = threadIdx.x >> 5;      // 0..15
        const int pr = threadIdx.x & 31;
        float hsum = 0.f;
        const float* wq = wpost + (size_t)(qbase + qi) * NCH;
        #pragma unroll 4
        for (int k = pr; k < NCH; k += 32) hsum += wq[k];
        #pragma unroll
        for (int off = 16; off; off >>= 1) hsum += __shfl_down(hsum, off, 32);
        if (pr == 0) {
            const float dtf   = (float)(*dtp);
            const float alpha = dtf * 1e-3f;
            hfs[qi] = -0.001f * (alpha * (hsum * (1.0f / (float)(BB * TT)) - 0.1f));
        }
    }

    float sx = 0.f, sy = 0.f;
    #pragma unroll 8
    for (int k = kq * (NBLK / 8); k < (kq + 1) * (NBLK / 8); ++k) {
        const unsigned int v = part[(size_t)k * SLOTS + slot];
        const f16x2 h = __builtin_bit_cast(f16x2, v);
        sx += (float)h[0];
        sy += (float)h[1];
    }
    red[threadIdx.x] = make_float2(sx, sy);
    __syncthreads();
    if (threadIdx.x < 64) {
        float tx = red[s].x, ty = red[s].y;
        #pragma unroll
        for (int g = 1; g < 8; ++g) {
            const float2 v = red[g * 64 + s];
            tx += v.x; ty += v.y;
        }
        // un-permute slot -> (p, q)
        const int lane = slot & 63;
        const int rp   = (slot >> 6) & 1;
        const int wv   = slot >> 10;
        const int p    = wv * 16 + ((lane >> 4) << 2) + rp * 2;
        const int qi   = lane & 15;
        const int q    = qbase + qi;
        const float scale = (float)((0.005 - 0.00525) / (double)(BB * TT));
        const float hf = hfs[qi];
        out[p * NN + q]       = fmaf(tx, scale, hf * W[p * NN + q]);
        out[(p + 1) * NN + q] = fmaf(ty, scale, hf * W[(p + 1) * NN + q]);
    }
}

// fallback epilogue when S was atomically accumulated in d_out
__global__ void finalize_at(const float* __restrict__ wpost, const int* __restrict__ dtp,
                            const float* __restrict__ W, float* __restrict__ out)
{
    const int i = (blockIdx.x * 256 + threadIdx.x) * 2;
    const int q = i & 127;
    const float scale = (float)((0.005 - 0.00525) / (double)(BB * TT));
    const float dtf   = (float)(*dtp);
    const float alpha = dtf * 1e-3f;
    const float inv   = 1.0f / (float)(BB * TT);
    const float hf0   = -0.001f * (alpha * (wpost[q]     * inv - 0.1f));
    const float hf1   = -0.001f * (alpha * (wpost[q + 1] * inv - 0.1f));
    float2 sv = *(const float2*)(out + i);
    float2 w  = *(const float2*)(W + i);
    float2 o;
    o.x = fmaf(sv.x, scale, hf0 * w.x);
    o.y = fmaf(sv.y, scale, hf1 * w.y);
    *(float2*)(out + i) = o;
}

extern "C" void kernel_launch(void* const* d_in, const int* in_sizes, int n_in,
                              void* d_out, int out_size, void* d_ws, size_t ws_size,
                              hipStream_t stream)
{
    const float* pre  = (const float*)d_in[0];
    const float* post = (const float*)d_in[1];
    const float* W    = (const float*)d_in[2];
    const int*   dtp  = (const int*)d_in[3];
    float* out = (float*)d_out;

    const size_t part_bytes  = (size_t)NBLK * SLOTS * sizeof(unsigned int); // 8 MiB
    const size_t wpost_bytes = (size_t)NN * NCH * sizeof(float);            // 256 KiB
    const size_t need = part_bytes + wpost_bytes;

    if (ws_size >= need) {
        unsigned int* part = (unsigned int*)d_ws;
        float* wpost       = (float*)((char*)d_ws + part_bytes);
        hipLaunchKernelGGL((stdp_main<false>), dim3(NBLK), dim3(512), 0, stream,
                           pre, post, dtp, part, wpost, (float*)nullptr);
        hipLaunchKernelGGL(finalize_ws, dim3(SLOTS / 64), dim3(512), 0, stream,
                           part, wpost, dtp, W, out);
    } else {
        // atomic fallback: needs only 512 B of workspace
        float* wpost = (float*)d_ws;
        hipMemsetAsync(d_out, 0, OUTN * sizeof(float), stream);
        hipMemsetAsync(wpost, 0, NN * sizeof(float), stream);
        hipLaunchKernelGGL((stdp_main<true>), dim3(NBLK), dim3(512), 0, stream,
                           pre, post, dtp, (unsigned int*)nullptr, wpost, out);
        hipLaunchKernelGGL(finalize_at, dim3(OUTN / 512), dim3(256), 0, stream,
                           wpost, dtp, W, out);
    }
}